// Round 9
// baseline (216.459 us; speedup 1.0000x reference)
//
#include <hip/hip_runtime.h>

// SimVQuantizer: B=8, D=128 (N_CB=8 x CDIM=16), H=W=32 -> 8192 pixels.
// Outputs (FLOAT32, concatenated flat):
//   quantized  [8,128,32,32]  = 1048576   @ 0
//   indices    [8,8,32,32]    =   65536   @ 1048576
//   commitment scalar         =       1   @ 1114112
//   new_codebooks [8,1024,16] =  131072   @ 1114113
//   new_count  [8,1024]       =    8192   @ 1245185
//   new_weight [8,1024,16]    =  131072   @ 1253377

#define NCB   8
#define VOCAB 1024
#define CDIM  16
#define NPIX  8192   // B*H*W
#define HW    1024   // H*W

#define OFF_QUANT  0
#define OFF_IDX    1048576
#define OFF_COMMIT 1114112
#define OFF_NCB    1114113
#define OFF_NCNT   1245185
#define OFF_NWT    1253377

// workspace layout (floats):
//   counts_p [8][2][1024]      @ 0       (per-(c,half) partial counts)
//   sums_p   [8][16][2][1024]  @ 16384   (per-(c,d,half) partial sums)
//   commit_arr [1024]          @ 278528  (per-assign-block partials)
//   ctr      [8] (uint)        @ 279552  (finisher election; zeroed by
//                                         k_assign block 0 each launch)
// No memset: every word is written before it is read.
#define WS_CNTP_OFF 0
#define WS_SUMP_OFF (NCB * 2 * VOCAB)
#define WS_CARR_OFF (NCB * 2 * VOCAB + NCB * CDIM * 2 * VOCAB)
#define WS_CTR_OFF  (WS_CARR_OFF + 1024)

// numpy pairwise_sum (order-preserving 8-accumulator) for n=16:
// r[j] = a[j] + a[j+8];  res = ((r0+r1)+(r2+r3)) + ((r4+r5)+(r6+r7))
__device__ __forceinline__ float npsum16(const float m[16]) {
#pragma clang fp contract(off)
  float r0 = m[0] + m[8];
  float r1 = m[1] + m[9];
  float r2 = m[2] + m[10];
  float r3 = m[3] + m[11];
  float r4 = m[4] + m[12];
  float r5 = m[5] + m[13];
  float r6 = m[6] + m[14];
  float r7 = m[7] + m[15];
  return ((r0 + r1) + (r2 + r3)) + ((r4 + r5) + (r6 + r7));
}

__device__ __forceinline__ float npsum16sq(const float a[16]) {
#pragma clang fp contract(off)
  float m[16];
#pragma unroll
  for (int d = 0; d < 16; ++d) m[d] = a[d] * a[d];
  return npsum16(m);
}

// One entry's distance + argmin step (v8 scalar form — v9's f32x2 packing
// was neutral: VOP3P needs VGPR operands, the SGPR entries got v_mov'd).
// numpy einsum (optimize=False) contig order, then (z2 - 2*dot) + c2.
__device__ __forceinline__ void proc_entry(const float zv[16],
                                           const float e[16], float c2v,
                                           float z2, int idx, float& best,
                                           int& bi) {
#pragma clang fp contract(off)
  float m[16];
#pragma unroll
  for (int d = 0; d < 16; ++d) m[d] = zv[d] * e[d];
  float l0 = (m[0] + m[4]) + (m[8] + m[12]);
  float l1 = (m[1] + m[5]) + (m[9] + m[13]);
  float l2 = (m[2] + m[6]) + (m[10] + m[14]);
  float l3 = (m[3] + m[7]) + (m[11] + m[15]);
  const float dot = (l0 + l1) + (l2 + l3);
  const float d2 = (z2 - 2.0f * dot) + c2v;
  const bool lt = d2 < best;  // strict: ascending scan -> first-wins
  best = lt ? d2 : best;
  bi = lt ? idx : bi;
}

// v10 k_assign: exact v8 (control: 64-65us, VALUBusy 62%), minus the stray
// no-op atomicAdd, plus zeroing the 8 finisher counters (block 0).
__global__ __launch_bounds__(512, 4) void k_assign(
    const float* __restrict__ z, const float* __restrict__ cb,
    float* __restrict__ out, float* __restrict__ ws_commit_arr,
    unsigned int* __restrict__ ws_ctr) {
  __shared__ float s_c2[VOCAB];    // 4KB
  __shared__ float s_best[8 * 64]; // 2KB
  __shared__ int s_bi[8 * 64];     // 2KB

  const int c = blockIdx.x >> 7;
  const int pchunk = blockIdx.x & 127;
  const int t = threadIdx.x;
  const int pix = t & 63;
  const int w = t >> 6;
  // provably wave-uniform wave id -> scalar (SGPR) entry addressing below
  const int wu = __builtin_amdgcn_readfirstlane(w);

  if (blockIdx.x == 0 && t < NCB) ws_ctr[t] = 0u;  // visible at k_stats start

  const float* cbc = cb + (size_t)c * VOCAB * CDIM;

  // ||cb||^2 for all 1024 entries (np.sum(cb*cb,-1), pairwise 8-acc order)
  for (int v = t; v < VOCAB; v += 512) {
    float e[16];
#pragma unroll
    for (int d = 0; d < 16; ++d) e[d] = cbc[(size_t)v * CDIM + d];
    s_c2[v] = npsum16sq(e);
  }

  const int n = pchunk * 64 + pix;  // pixel id in [0, 8192)
  const int b = n >> 10;            // batch
  const int hw = n & 1023;          // h*W + w

  // zp[n,c,d] = z[b, c*16+d, h, w]; 64-lane coalesced per d
  const float* zbase = z + ((size_t)(b * 128 + c * 16)) * HW + hw;
  float zv[16];
#pragma unroll
  for (int d = 0; d < 16; ++d) zv[d] = zbase[(size_t)d * HW];

  const float z2 = npsum16sq(zv);

  __syncthreads();  // s_c2 ready

  // wave wu scans entries [wu*128, wu*128+128), ascending
  const int vbase = wu * 128;
  const float* ep = cbc + (size_t)vbase * CDIM;  // uniform (SGPR) pointer

  float best = INFINITY;
  int bi = 0;

#pragma unroll 2
  for (int k = 0; k < 128; k += 2) {
    // two entries per body; unroll 2 -> 4 entries of load-ahead slack for
    // the scheduler. All addresses uniform -> scalar loads.
    float ea[16], eb[16];
#pragma unroll
    for (int d = 0; d < 16; ++d) ea[d] = ep[(size_t)k * CDIM + d];
#pragma unroll
    for (int d = 0; d < 16; ++d) eb[d] = ep[(size_t)(k + 1) * CDIM + d];
    const float cv0 = s_c2[vbase + k];
    const float cv1 = s_c2[vbase + k + 1];
    proc_entry(zv, ea, cv0, z2, vbase + k, best, bi);
    proc_entry(zv, eb, cv1, z2, vbase + k + 1, best, bi);
  }

  s_best[w * 64 + pix] = best;
  s_bi[w * 64 + pix] = bi;
  __syncthreads();

  // wave 0: combine the 8 per-wave candidates. Wave slices are disjoint
  // ascending ranges; break float ties by lower index -> np.argmin
  // first-wins exactly.
  if (t < 64) {
    best = s_best[t];
    bi = s_bi[t];
#pragma unroll
    for (int s = 1; s < 8; ++s) {
      const float ob = s_best[s * 64 + t];
      const int oi = s_bi[s * 64 + t];
      const bool take = (ob < best) || (ob == best && oi < bi);
      best = take ? ob : best;
      bi = take ? oi : bi;
    }

    // t<64 => wave 0, pix == t: zv holds THIS pixel's z (bit-identical)
    const float* qe = cbc + (size_t)bi * CDIM;  // winning entry (L2-hot)
    float comm = 0.f;
#pragma unroll
    for (int d = 0; d < 16; ++d) {
      float zq = qe[d];
      float diff, qst;
      {
#pragma clang fp contract(off)
        diff = zv[d] - zq;
        qst = zv[d] + (zq - zv[d]);  // zq_st = zp + (zq - zp), as np computes
      }
      comm += diff * diff;
      out[OFF_QUANT + ((size_t)(b * 128 + c * 16 + d)) * HW + hw] = qst;
    }
    out[OFF_IDX + ((size_t)(b * NCB + c)) * HW + hw] = (float)bi;

    // commitment partial: ONE plain store per block (no atomics)
#pragma unroll
    for (int off = 32; off; off >>= 1) comm += __shfl_down(comm, off);
    if (t == 0) ws_commit_arr[blockIdx.x] = comm;
  }
}

// k_stats v10: v8's 256-block stats (4 hoisted idx + 4 z loads, 4-5 LDS
// atomics/thread — proven fast) + "last block per c finishes" tail that
// replicates v8's k_update BIT-EXACTLY (same 256-thread psum tree, same
// per-element formulas), eliminating the third kernel and its boundary.
// Election: after writing partials, __threadfence() (agent-scope release:
// L2 writeback) then atomicAdd on ctr[c]; the 32nd block acquires and
// runs the update for c. No spinning -> no co-residency assumption.
__global__ __launch_bounds__(1024, 4) void k_stats(
    const float* __restrict__ z, const float* __restrict__ outbuf,
    const float* __restrict__ ema_count, const float* __restrict__ ema_weight,
    float* __restrict__ ws_counts_p, float* __restrict__ ws_sums_p,
    const float* __restrict__ ws_commit_arr, unsigned int* __restrict__ ws_ctr,
    float* __restrict__ out) {
  __shared__ float s_sum[VOCAB];  // 4KB
  __shared__ float s_cnt[VOCAB];  // 4KB (d==0 blocks only)
  __shared__ float s_red[4];
  __shared__ float s_n;
  __shared__ double s_dred[4];
  __shared__ int s_last;

  const int c = blockIdx.x >> 5;
  const int d = (blockIdx.x >> 1) & 15;
  const int half = blockIdx.x & 1;
  const int t = threadIdx.x;

  s_sum[t] = 0.f;
  if (d == 0) s_cnt[t] = 0.f;

  // hoist all loads: 4 idx + 4 z, independent -> one latency exposure
  int bidx[4];
  float zval[4];
#pragma unroll
  for (int k = 0; k < 4; ++k) {
    const int bb = half * 4 + k;  // batch
    bidx[k] = (int)outbuf[OFF_IDX + ((size_t)(bb * NCB + c)) * HW + t];
    zval[k] = z[((size_t)(bb * 128 + c * 16 + d)) * HW + t];
  }
  __syncthreads();  // zero-init visible

#pragma unroll
  for (int k = 0; k < 4; ++k) {
    atomicAdd(&s_sum[bidx[k]], zval[k]);  // ds_add_f32, banked
    if (d == 0) atomicAdd(&s_cnt[bidx[k]], 1.0f);
  }
  __syncthreads();

  ws_sums_p[((size_t)((c * CDIM + d) * 2 + half)) * VOCAB + t] = s_sum[t];
  if (d == 0) ws_counts_p[(c * 2 + half) * VOCAB + t] = s_cnt[t];

  // ---- finisher election (one block per c runs the update) ----
  __threadfence();  // release: partials visible device-wide
  if (t == 0) s_last = (atomicAdd(&ws_ctr[c], 1u) == 31u);
  __syncthreads();
  if (!s_last) return;
  __threadfence();  // acquire before reading other blocks' partials

  const float* cp0 = ws_counts_p + (c * 2 + 0) * VOCAB;
  const float* cp1 = ws_counts_p + (c * 2 + 1) * VOCAB;

  // nsum: exact v8 k_update tree (256 threads, 4-strided psum, 64-lane
  // shuffle, s_red[4]) -> bit-identical nsum
  if (t < 256) {
    float psum = 0.f;
#pragma unroll
    for (int k = 0; k < 4; ++k) {
      const int v = k * 256 + t;
      psum +=
          0.99f * ema_count[c * VOCAB + v] + 0.01f * (cp0[v] + cp1[v]);
    }
#pragma unroll
    for (int off = 32; off; off >>= 1) psum += __shfl_down(psum, off);
    if ((t & 63) == 0) s_red[t >> 6] = psum;
  }
  __syncthreads();
  if (t == 0) s_n = (s_red[0] + s_red[1]) + (s_red[2] + s_red[3]);
  __syncthreads();
  const float nsum = s_n;
  const float veps = 0.01024f;  // VOCAB * 1e-5

  // new_count: same per-element formula as v8 (v = t covers all 1024)
  out[OFF_NCNT + c * VOCAB + t] =
      0.99f * ema_count[c * VOCAB + t] + 0.01f * (cp0[t] + cp1[t]);

  // new_weight / new_codebooks: same per-element formulas as v8, 16
  // elements per thread, coalesced
#pragma unroll
  for (int j = 0; j < 16; ++j) {
    const int i = j * 1024 + t;  // element within codebook c
    const int v = i >> 4;
    const int dd = i & 15;
    const float nc =
        0.99f * ema_count[c * VOCAB + v] + 0.01f * (cp0[v] + cp1[v]);
    const float cnt = (nc + 1e-5f) / (nsum + veps) * nsum;
    const size_t gi = (size_t)c * VOCAB * CDIM + i;
    const float s0 = ws_sums_p[((size_t)((c * CDIM + dd) * 2 + 0)) * VOCAB + v];
    const float s1 = ws_sums_p[((size_t)((c * CDIM + dd) * 2 + 1)) * VOCAB + v];
    const float nw = 0.99f * ema_weight[gi] + 0.01f * (s0 + s1);
    out[OFF_NWT + gi] = nw;
    out[OFF_NCB + gi] = nw / cnt;
  }

  // commitment: c==0 finisher, exact v8 block-0 reduction (256 threads)
  if (c == 0) {
    if (t < 256) {
      double ps = 0.0;
#pragma unroll
      for (int k = 0; k < 4; ++k) ps += (double)ws_commit_arr[k * 256 + t];
#pragma unroll
      for (int off = 32; off; off >>= 1) ps += __shfl_down(ps, off);
      if ((t & 63) == 0) s_dred[t >> 6] = ps;
    }
    __syncthreads();
    if (t == 0)
      out[OFF_COMMIT] =
          (float)(((s_dred[0] + s_dred[1]) + (s_dred[2] + s_dred[3])) /
                  1048576.0);
  }
}

extern "C" void kernel_launch(void* const* d_in, const int* in_sizes, int n_in,
                              void* d_out, int out_size, void* d_ws,
                              size_t ws_size, hipStream_t stream) {
  const float* z = (const float*)d_in[0];
  const float* codebooks = (const float*)d_in[1];
  const float* ema_count = (const float*)d_in[2];
  const float* ema_weight = (const float*)d_in[3];
  float* out = (float*)d_out;

  float* wsf = (float*)d_ws;
  float* ws_counts_p = wsf + WS_CNTP_OFF;
  float* ws_sums_p = wsf + WS_SUMP_OFF;
  float* ws_commit_arr = wsf + WS_CARR_OFF;
  unsigned int* ws_ctr = (unsigned int*)(wsf + WS_CTR_OFF);

  // no memset: all workspace words (incl. ctr, zeroed in k_assign) are
  // written before being read

  k_assign<<<dim3(1024), dim3(512), 0, stream>>>(z, codebooks, out,
                                                 ws_commit_arr, ws_ctr);
  k_stats<<<dim3(256), dim3(1024), 0, stream>>>(z, out, ema_count, ema_weight,
                                                ws_counts_p, ws_sums_p,
                                                ws_commit_arr, ws_ctr, out);
}

// Round 10
// 143.211 us; speedup vs baseline: 1.5115x; 1.5115x over previous
//
#include <hip/hip_runtime.h>

// SimVQuantizer: B=8, D=128 (N_CB=8 x CDIM=16), H=W=32 -> 8192 pixels.
// Outputs (FLOAT32, concatenated flat):
//   quantized  [8,128,32,32]  = 1048576   @ 0
//   indices    [8,8,32,32]    =   65536   @ 1048576
//   commitment scalar         =       1   @ 1114112
//   new_codebooks [8,1024,16] =  131072   @ 1114113
//   new_count  [8,1024]       =    8192   @ 1245185
//   new_weight [8,1024,16]    =  131072   @ 1253377

#define NCB   8
#define VOCAB 1024
#define CDIM  16
#define NPIX  8192   // B*H*W
#define HW    1024   // H*W

#define OFF_QUANT  0
#define OFF_IDX    1048576
#define OFF_COMMIT 1114112
#define OFF_NCB    1114113
#define OFF_NCNT   1245185
#define OFF_NWT    1253377

// workspace layout (floats):
//   counts_p [8][2][1024]      @ 0       (per-(c,half) partial counts)
//   sums_p   [8][16][2][1024]  @ 16384   (per-(c,d,half) partial sums)
//   commit_arr [1024]          @ 278528  (per-assign-block partials)
// No memset: every word is written before it is read.
// NOTE (v10 lesson): NO device-scope fences / finisher patterns — a
// __threadfence per block forces per-XCD L2 writebacks (~100x costlier
// than a kernel boundary on gfx950). Stream boundaries are the cheap sync.
#define WS_CNTP_OFF 0
#define WS_SUMP_OFF (NCB * 2 * VOCAB)
#define WS_CARR_OFF (NCB * 2 * VOCAB + NCB * CDIM * 2 * VOCAB)

// numpy pairwise_sum (order-preserving 8-accumulator) for n=16:
// r[j] = a[j] + a[j+8];  res = ((r0+r1)+(r2+r3)) + ((r4+r5)+(r6+r7))
__device__ __forceinline__ float npsum16(const float m[16]) {
#pragma clang fp contract(off)
  float r0 = m[0] + m[8];
  float r1 = m[1] + m[9];
  float r2 = m[2] + m[10];
  float r3 = m[3] + m[11];
  float r4 = m[4] + m[12];
  float r5 = m[5] + m[13];
  float r6 = m[6] + m[14];
  float r7 = m[7] + m[15];
  return ((r0 + r1) + (r2 + r3)) + ((r4 + r5) + (r6 + r7));
}

__device__ __forceinline__ float npsum16sq(const float a[16]) {
#pragma clang fp contract(off)
  float m[16];
#pragma unroll
  for (int d = 0; d < 16; ++d) m[d] = a[d] * a[d];
  return npsum16(m);
}

// One entry's distance + argmin step. numpy einsum (optimize=False) npyv
// contig order for n=16, then (z2 - 2*dot) + c2 — bit-identical to v1.
__device__ __forceinline__ void proc_entry(const float zv[16],
                                           const float e[16], float c2v,
                                           float z2, int idx, float& best,
                                           int& bi) {
#pragma clang fp contract(off)
  float m[16];
#pragma unroll
  for (int d = 0; d < 16; ++d) m[d] = zv[d] * e[d];
  float l0 = (m[0] + m[4]) + (m[8] + m[12]);
  float l1 = (m[1] + m[5]) + (m[9] + m[13]);
  float l2 = (m[2] + m[6]) + (m[10] + m[14]);
  float l3 = (m[3] + m[7]) + (m[11] + m[15]);
  const float dot = (l0 + l1) + (l2 + l3);
  const float d2 = (z2 - 2.0f * dot) + c2v;
  const bool lt = d2 < best;  // strict: ascending scan -> first-wins
  best = lt ? d2 : best;
  bi = lt ? idx : bi;
}

// v11 k_assign: v8 shell, but the entry stream moves from SMEM (s_load,
// out-of-order -> only lgkmcnt(0) drains possible, ~25us exposed latency)
// to per-lane VMEM float4 loads at a wave-uniform address (one coalesced
// 16B broadcast per load, L1/L2-hot) with an explicit cur/nxt prefetch:
// VMEM supports counted vmcnt(N) pipelines the compiler manages in plain
// C. The opaque `vz` (a shuffled 0) stops uniformity analysis from
// scalarizing the loads back to s_load. Same bytes, same arithmetic.
__global__ __launch_bounds__(512, 4) void k_assign(
    const float* __restrict__ z, const float* __restrict__ cb,
    float* __restrict__ out, float* __restrict__ ws_commit_arr) {
  __shared__ float s_c2[VOCAB];    // 4KB
  __shared__ float s_best[8 * 64]; // 2KB
  __shared__ int s_bi[8 * 64];     // 2KB

  const int c = blockIdx.x >> 7;
  const int pchunk = blockIdx.x & 127;
  const int t = threadIdx.x;
  const int pix = t & 63;
  const int w = t >> 6;
  const int wu = __builtin_amdgcn_readfirstlane(w);  // uniform wave id

  const float* cbc = cb + (size_t)c * VOCAB * CDIM;

  // ||cb||^2 for all 1024 entries (np.sum(cb*cb,-1), pairwise 8-acc order)
  for (int v = t; v < VOCAB; v += 512) {
    float e[16];
#pragma unroll
    for (int d = 0; d < 16; ++d) e[d] = cbc[(size_t)v * CDIM + d];
    s_c2[v] = npsum16sq(e);
  }

  const int n = pchunk * 64 + pix;  // pixel id in [0, 8192)
  const int b = n >> 10;            // batch
  const int hw = n & 1023;          // h*W + w

  // zp[n,c,d] = z[b, c*16+d, h, w]; 64-lane coalesced per d
  const float* zbase = z + ((size_t)(b * 128 + c * 16)) * HW + hw;
  float zv[16];
#pragma unroll
  for (int d = 0; d < 16; ++d) zv[d] = zbase[(size_t)d * HW];

  const float z2 = npsum16sq(zv);

  __syncthreads();  // s_c2 ready

  // wave wu scans entries [wu*128, wu*128+128), ascending.
  const int vbase = wu * 128;
  // opaque zero in a VGPR: keeps the entry loads on the VMEM path
  const int vz = __shfl(0, pix);
  const float4* ep4 =
      reinterpret_cast<const float4*>(cbc + (size_t)vbase * CDIM) + vz;

  float best = INFINITY;
  int bi = 0;

  // software pipeline: entry k in cur, entry k+1 loading into nxt
  float4 c0 = ep4[0], c1 = ep4[1], c2x = ep4[2], c3 = ep4[3];
#pragma unroll 2
  for (int k = 0; k < 128; ++k) {
    float4 n0, n1, n2, n3;
    if (k < 127) {
      const float4* np4 = ep4 + (size_t)(k + 1) * 4;
      n0 = np4[0]; n1 = np4[1]; n2 = np4[2]; n3 = np4[3];
    }
    float e[16];
    e[0] = c0.x;  e[1] = c0.y;  e[2] = c0.z;  e[3] = c0.w;
    e[4] = c1.x;  e[5] = c1.y;  e[6] = c1.z;  e[7] = c1.w;
    e[8] = c2x.x; e[9] = c2x.y; e[10] = c2x.z; e[11] = c2x.w;
    e[12] = c3.x; e[13] = c3.y; e[14] = c3.z; e[15] = c3.w;
    proc_entry(zv, e, s_c2[vbase + k], z2, vbase + k, best, bi);
    c0 = n0; c1 = n1; c2x = n2; c3 = n3;
  }

  s_best[w * 64 + pix] = best;
  s_bi[w * 64 + pix] = bi;
  __syncthreads();

  // wave 0: combine the 8 per-wave candidates. Wave slices are disjoint
  // ascending ranges; break float ties by lower index -> np.argmin
  // first-wins exactly.
  if (t < 64) {
    best = s_best[t];
    bi = s_bi[t];
#pragma unroll
    for (int s = 1; s < 8; ++s) {
      const float ob = s_best[s * 64 + t];
      const int oi = s_bi[s * 64 + t];
      const bool take = (ob < best) || (ob == best && oi < bi);
      best = take ? ob : best;
      bi = take ? oi : bi;
    }

    // t<64 => wave 0, pix == t: zv holds THIS pixel's z (bit-identical)
    const float* qe = cbc + (size_t)bi * CDIM;  // winning entry (L2-hot)
    float comm = 0.f;
#pragma unroll
    for (int d = 0; d < 16; ++d) {
      float zq = qe[d];
      float diff, qst;
      {
#pragma clang fp contract(off)
        diff = zv[d] - zq;
        qst = zv[d] + (zq - zv[d]);  // zq_st = zp + (zq - zp), as np computes
      }
      comm += diff * diff;
      out[OFF_QUANT + ((size_t)(b * 128 + c * 16 + d)) * HW + hw] = qst;
    }
    out[OFF_IDX + ((size_t)(b * NCB + c)) * HW + hw] = (float)bi;

    // commitment partial: ONE plain store per block (no atomics)
#pragma unroll
    for (int off = 32; off; off >>= 1) comm += __shfl_down(comm, off);
    if (t == 0) ws_commit_arr[blockIdx.x] = comm;
  }
}

// k_stats: exact v8 (proven fast). 256 blocks = (c, d, half) x 1024
// threads; hoisted loads (one latency exposure), LDS-atomic binning,
// dense partial writes, zero global atomics, zero fences.
__global__ __launch_bounds__(1024, 4) void k_stats(
    const float* __restrict__ z, const float* __restrict__ outbuf,
    float* __restrict__ ws_counts_p, float* __restrict__ ws_sums_p) {
  __shared__ float s_sum[VOCAB];  // 4KB
  __shared__ float s_cnt[VOCAB];  // 4KB (d==0 blocks only)
  const int c = blockIdx.x >> 5;
  const int d = (blockIdx.x >> 1) & 15;
  const int half = blockIdx.x & 1;
  const int t = threadIdx.x;

  s_sum[t] = 0.f;
  if (d == 0) s_cnt[t] = 0.f;

  // hoist all loads: 4 idx + 4 z, independent -> one latency exposure
  int bidx[4];
  float zval[4];
#pragma unroll
  for (int k = 0; k < 4; ++k) {
    const int bb = half * 4 + k;  // batch
    bidx[k] = (int)outbuf[OFF_IDX + ((size_t)(bb * NCB + c)) * HW + t];
    zval[k] = z[((size_t)(bb * 128 + c * 16 + d)) * HW + t];
  }
  __syncthreads();  // zero-init visible

#pragma unroll
  for (int k = 0; k < 4; ++k) {
    atomicAdd(&s_sum[bidx[k]], zval[k]);  // ds_add_f32, banked
    if (d == 0) atomicAdd(&s_cnt[bidx[k]], 1.0f);
  }
  __syncthreads();

  ws_sums_p[((size_t)((c * CDIM + d) * 2 + half)) * VOCAB + t] = s_sum[t];
  if (d == 0) ws_counts_p[(c * 2 + half) * VOCAB + t] = s_cnt[t];
}

// k_update: exact v8. 64 blocks x 256 threads; block = (c, part).
__global__ __launch_bounds__(256) void k_update(
    const float* __restrict__ ema_count, const float* __restrict__ ema_weight,
    const float* __restrict__ ws_counts_p, const float* __restrict__ ws_sums_p,
    const float* __restrict__ ws_commit_arr, float* __restrict__ out) {
  const int c = blockIdx.x >> 3;
  const int part = blockIdx.x & 7;
  const int t = threadIdx.x;
  __shared__ float s_red[4];
  __shared__ float s_n;
  __shared__ double s_dred[4];

  const float* cp0 = ws_counts_p + (c * 2 + 0) * VOCAB;
  const float* cp1 = ws_counts_p + (c * 2 + 1) * VOCAB;

  float psum = 0.f;
#pragma unroll
  for (int k = 0; k < 4; ++k) {
    const int v = k * 256 + t;
    psum += 0.99f * ema_count[c * VOCAB + v] + 0.01f * (cp0[v] + cp1[v]);
  }
#pragma unroll
  for (int off = 32; off; off >>= 1) psum += __shfl_down(psum, off);
  if ((t & 63) == 0) s_red[t >> 6] = psum;
  __syncthreads();
  if (t == 0) s_n = (s_red[0] + s_red[1]) + (s_red[2] + s_red[3]);
  __syncthreads();
  const float nsum = s_n;
  const float veps = 0.01024f;  // VOCAB * 1e-5

  // new_count: 128 entries per block
  if (t < 128) {
    const int v = part * 128 + t;
    out[OFF_NCNT + c * VOCAB + v] =
        0.99f * ema_count[c * VOCAB + v] + 0.01f * (cp0[v] + cp1[v]);
  }

  // new_weight / new_codebooks: 2048 elements per block, coalesced stores;
  // sum partials read from [c][d][half][v] layout (L2-hot, 1MB total)
#pragma unroll
  for (int k = 0; k < 8; ++k) {
    const int i = part * 2048 + k * 256 + t;  // element within codebook c
    const int v = i >> 4;
    const int d = i & 15;
    const float nc =
        0.99f * ema_count[c * VOCAB + v] + 0.01f * (cp0[v] + cp1[v]);
    const float cnt = (nc + 1e-5f) / (nsum + veps) * nsum;
    const size_t gi = (size_t)c * VOCAB * CDIM + i;
    const float s0 = ws_sums_p[((size_t)((c * CDIM + d) * 2 + 0)) * VOCAB + v];
    const float s1 = ws_sums_p[((size_t)((c * CDIM + d) * 2 + 1)) * VOCAB + v];
    const float nw = 0.99f * ema_weight[gi] + 0.01f * (s0 + s1);
    out[OFF_NWT + gi] = nw;
    out[OFF_NCB + gi] = nw / cnt;
  }

  if (blockIdx.x == 0) {
    double ps = 0.0;
#pragma unroll
    for (int k = 0; k < 4; ++k) ps += (double)ws_commit_arr[k * 256 + t];
#pragma unroll
    for (int off = 32; off; off >>= 1) ps += __shfl_down(ps, off);
    if ((t & 63) == 0) s_dred[t >> 6] = ps;
    __syncthreads();
    if (t == 0)
      out[OFF_COMMIT] =
          (float)(((s_dred[0] + s_dred[1]) + (s_dred[2] + s_dred[3])) /
                  1048576.0);
  }
}

extern "C" void kernel_launch(void* const* d_in, const int* in_sizes, int n_in,
                              void* d_out, int out_size, void* d_ws,
                              size_t ws_size, hipStream_t stream) {
  const float* z = (const float*)d_in[0];
  const float* codebooks = (const float*)d_in[1];
  const float* ema_count = (const float*)d_in[2];
  const float* ema_weight = (const float*)d_in[3];
  float* out = (float*)d_out;

  float* wsf = (float*)d_ws;
  float* ws_counts_p = wsf + WS_CNTP_OFF;
  float* ws_sums_p = wsf + WS_SUMP_OFF;
  float* ws_commit_arr = wsf + WS_CARR_OFF;

  // no memset: all workspace words are written before being read

  k_assign<<<dim3(1024), dim3(512), 0, stream>>>(z, codebooks, out,
                                                 ws_commit_arr);
  k_stats<<<dim3(256), dim3(1024), 0, stream>>>(z, out, ws_counts_p,
                                                ws_sums_p);
  k_update<<<dim3(64), dim3(256), 0, stream>>>(ema_count, ema_weight,
                                               ws_counts_p, ws_sums_p,
                                               ws_commit_arr, out);
}

// Round 11
// 134.384 us; speedup vs baseline: 1.6107x; 1.0657x over previous
//
#include <hip/hip_runtime.h>

// SimVQuantizer: B=8, D=128 (N_CB=8 x CDIM=16), H=W=32 -> 8192 pixels.
// Outputs (FLOAT32, concatenated flat):
//   quantized  [8,128,32,32]  = 1048576   @ 0
//   indices    [8,8,32,32]    =   65536   @ 1048576
//   commitment scalar         =       1   @ 1114112
//   new_codebooks [8,1024,16] =  131072   @ 1114113
//   new_count  [8,1024]       =    8192   @ 1245185
//   new_weight [8,1024,16]    =  131072   @ 1253377

#define NCB   8
#define VOCAB 1024
#define CDIM  16
#define NPIX  8192   // B*H*W
#define HW    1024   // H*W

#define OFF_QUANT  0
#define OFF_IDX    1048576
#define OFF_COMMIT 1114112
#define OFF_NCB    1114113
#define OFF_NCNT   1245185
#define OFF_NWT    1253377

// workspace layout (floats):
//   counts_p [8][2][1024]      @ 0       (per-(c,half) partial counts)
//   sums_p   [8][16][2][1024]  @ 16384   (per-(c,d,half) partial sums)
//   commit_arr [1024]          @ 278528  (per-assign-block partials)
// No memset: every word is written before it is read.
// Lessons pinned: no global atomics in hot paths (v6); no per-block
// __threadfence finisher patterns (v10: per-XCD L2 writebacks ~100x a
// kernel boundary); SMEM s_loads can't pipeline (out-of-order, lgkmcnt(0)
// only); uniformity can't be hidden via shuffle-of-constant (v11).
#define WS_CNTP_OFF 0
#define WS_SUMP_OFF (NCB * 2 * VOCAB)
#define WS_CARR_OFF (NCB * 2 * VOCAB + NCB * CDIM * 2 * VOCAB)

typedef __attribute__((ext_vector_type(2))) float f32x2;

// numpy pairwise_sum (order-preserving 8-accumulator) for n=16:
// r[j] = a[j] + a[j+8];  res = ((r0+r1)+(r2+r3)) + ((r4+r5)+(r6+r7))
__device__ __forceinline__ float npsum16(const float m[16]) {
#pragma clang fp contract(off)
  float r0 = m[0] + m[8];
  float r1 = m[1] + m[9];
  float r2 = m[2] + m[10];
  float r3 = m[3] + m[11];
  float r4 = m[4] + m[12];
  float r5 = m[5] + m[13];
  float r6 = m[6] + m[14];
  float r7 = m[7] + m[15];
  return ((r0 + r1) + (r2 + r3)) + ((r4 + r5) + (r6 + r7));
}

__device__ __forceinline__ float npsum16sq(const float a[16]) {
#pragma clang fp contract(off)
  float m[16];
#pragma unroll
  for (int d = 0; d < 16; ++d) m[d] = a[d] * a[d];
  return npsum16(m);
}

// One entry's distance + argmin step, packed-pair (VOP3P-eligible) form.
// BIT-EXACT to numpy's einsum contig tree (validated by v9's passing run):
//   m[j] = (m_{2j}, m_{2j+1});  (l0,l1) = (m[0]+m[2]) + (m[4]+m[6]);
//   (l2,l3) = (m[1]+m[3]) + (m[5]+m[7]);  dot = (l0+l1)+(l2+l3);
//   d2 = (z2 - 2*dot) + c2.
// Entries arrive as float4s from ds_read_b128 (VGPRs, 4-aligned -> the
// f32x2 halves are register-pair aliases) so BOTH pk operands are VGPRs —
// the condition v9 lacked (its SGPR sources forced movs / scalarization).
__device__ __forceinline__ void proc_entry_pk(const f32x2 zp[8], float4 q0,
                                              float4 q1, float4 q2, float4 q3,
                                              float c2v, float z2, int idx,
                                              float& best, int& bi) {
#pragma clang fp contract(off)
  f32x2 e[8];
  e[0] = f32x2{q0.x, q0.y}; e[1] = f32x2{q0.z, q0.w};
  e[2] = f32x2{q1.x, q1.y}; e[3] = f32x2{q1.z, q1.w};
  e[4] = f32x2{q2.x, q2.y}; e[5] = f32x2{q2.z, q2.w};
  e[6] = f32x2{q3.x, q3.y}; e[7] = f32x2{q3.z, q3.w};
  f32x2 m[8];
#pragma unroll
  for (int j = 0; j < 8; ++j) m[j] = zp[j] * e[j];
  const f32x2 l01 = (m[0] + m[2]) + (m[4] + m[6]);
  const f32x2 l23 = (m[1] + m[3]) + (m[5] + m[7]);
  const float dot = (l01.x + l01.y) + (l23.x + l23.y);
  const float d2 = (z2 - 2.0f * dot) + c2v;
  const bool lt = d2 < best;  // strict: ascending scan -> first-wins
  best = lt ? d2 : best;
  bi = lt ? idx : bi;
}

// v12 k_assign: entries from LDS (full 1024-entry codebook staged once,
// 64KB) via wave-uniform broadcast ds_read_b128 + packed-pair math.
// Rationale: SMEM path (v8, 65us) is stall-bound and unpipelineable
// (out-of-order s_loads -> lgkmcnt(0) drains). ds_read results return
// IN ORDER -> compiler emits counted lgkmcnt(N) pipelines (m97), and
// VGPR-resident entries make VOP3P legal (~23 vs ~37 instr/entry).
__global__ __launch_bounds__(512, 4) void k_assign(
    const float* __restrict__ z, const float* __restrict__ cb,
    float* __restrict__ out, float* __restrict__ ws_commit_arr) {
  __shared__ float s_cb[VOCAB * CDIM];  // 64KB: all 1024 entries
  __shared__ float s_c2[VOCAB];         // 4KB
  __shared__ float s_best[8 * 64];      // 2KB
  __shared__ int s_bi[8 * 64];          // 2KB

  const int c = blockIdx.x >> 7;
  const int pchunk = blockIdx.x & 127;
  const int t = threadIdx.x;
  const int pix = t & 63;
  const int w = t >> 6;
  const int wu = __builtin_amdgcn_readfirstlane(w);  // uniform wave id

  const float* cbc = cb + (size_t)c * VOCAB * CDIM;
  const float4* cb4 = reinterpret_cast<const float4*>(cbc);
  float4* s_cb4 = reinterpret_cast<float4*>(s_cb);

  // stage full codebook: 4096 float4, 8 per thread, coalesced (L2-hot)
#pragma unroll
  for (int i = 0; i < 8; ++i) s_cb4[i * 512 + t] = cb4[i * 512 + t];

  // ||cb||^2 for all 1024 entries (np.sum(cb*cb,-1), pairwise 8-acc order)
  for (int v = t; v < VOCAB; v += 512) {
    float e[16];
#pragma unroll
    for (int d = 0; d < 16; ++d) e[d] = cbc[(size_t)v * CDIM + d];
    s_c2[v] = npsum16sq(e);
  }

  const int n = pchunk * 64 + pix;  // pixel id in [0, 8192)
  const int b = n >> 10;            // batch
  const int hw = n & 1023;          // h*W + w

  // zp[n,c,d] = z[b, c*16+d, h, w]; 64-lane coalesced per d
  const float* zbase = z + ((size_t)(b * 128 + c * 16)) * HW + hw;
  float zv[16];
#pragma unroll
  for (int d = 0; d < 16; ++d) zv[d] = zbase[(size_t)d * HW];

  const float z2 = npsum16sq(zv);

  // natural-pair packing of z for the pk loop (aliases zv registers)
  f32x2 zp[8];
#pragma unroll
  for (int j = 0; j < 8; ++j) zp[j] = f32x2{zv[2 * j], zv[2 * j + 1]};

  __syncthreads();  // s_cb + s_c2 ready

  // wave wu scans entries [wu*128, wu*128+128), ascending; wave-uniform
  // LDS address -> broadcast reads, compiler-pipelined via counted lgkmcnt
  const int vbase = wu * 128;
  const float4* sl4 = s_cb4 + (size_t)vbase * 4;

  float best = INFINITY;
  int bi = 0;

#pragma unroll 2
  for (int k = 0; k < 128; k += 2) {
    const float4 a0 = sl4[k * 4 + 0], a1 = sl4[k * 4 + 1];
    const float4 a2 = sl4[k * 4 + 2], a3 = sl4[k * 4 + 3];
    const float4 b0 = sl4[k * 4 + 4], b1 = sl4[k * 4 + 5];
    const float4 b2 = sl4[k * 4 + 6], b3 = sl4[k * 4 + 7];
    const float cv0 = s_c2[vbase + k];
    const float cv1 = s_c2[vbase + k + 1];
    proc_entry_pk(zp, a0, a1, a2, a3, cv0, z2, vbase + k, best, bi);
    proc_entry_pk(zp, b0, b1, b2, b3, cv1, z2, vbase + k + 1, best, bi);
  }

  s_best[w * 64 + pix] = best;
  s_bi[w * 64 + pix] = bi;
  __syncthreads();

  // wave 0: combine the 8 per-wave candidates. Wave slices are disjoint
  // ascending ranges; break float ties by lower index -> np.argmin
  // first-wins exactly.
  if (t < 64) {
    best = s_best[t];
    bi = s_bi[t];
#pragma unroll
    for (int s = 1; s < 8; ++s) {
      const float ob = s_best[s * 64 + t];
      const int oi = s_bi[s * 64 + t];
      const bool take = (ob < best) || (ob == best && oi < bi);
      best = take ? ob : best;
      bi = take ? oi : bi;
    }

    // t<64 => wave 0, pix == t: zv holds THIS pixel's z (bit-identical)
    const float* qe = cbc + (size_t)bi * CDIM;  // winning entry (L2-hot)
    float comm = 0.f;
#pragma unroll
    for (int d = 0; d < 16; ++d) {
      float zq = qe[d];
      float diff, qst;
      {
#pragma clang fp contract(off)
        diff = zv[d] - zq;
        qst = zv[d] + (zq - zv[d]);  // zq_st = zp + (zq - zp), as np computes
      }
      comm += diff * diff;
      out[OFF_QUANT + ((size_t)(b * 128 + c * 16 + d)) * HW + hw] = qst;
    }
    out[OFF_IDX + ((size_t)(b * NCB + c)) * HW + hw] = (float)bi;

    // commitment partial: ONE plain store per block (no atomics)
#pragma unroll
    for (int off = 32; off; off >>= 1) comm += __shfl_down(comm, off);
    if (t == 0) ws_commit_arr[blockIdx.x] = comm;
  }
}

// k_stats: exact v8 (proven fast). 256 blocks = (c, d, half) x 1024
// threads; hoisted loads (one latency exposure), LDS-atomic binning,
// dense partial writes, zero global atomics, zero fences.
__global__ __launch_bounds__(1024, 4) void k_stats(
    const float* __restrict__ z, const float* __restrict__ outbuf,
    float* __restrict__ ws_counts_p, float* __restrict__ ws_sums_p) {
  __shared__ float s_sum[VOCAB];  // 4KB
  __shared__ float s_cnt[VOCAB];  // 4KB (d==0 blocks only)
  const int c = blockIdx.x >> 5;
  const int d = (blockIdx.x >> 1) & 15;
  const int half = blockIdx.x & 1;
  const int t = threadIdx.x;

  s_sum[t] = 0.f;
  if (d == 0) s_cnt[t] = 0.f;

  // hoist all loads: 4 idx + 4 z, independent -> one latency exposure
  int bidx[4];
  float zval[4];
#pragma unroll
  for (int k = 0; k < 4; ++k) {
    const int bb = half * 4 + k;  // batch
    bidx[k] = (int)outbuf[OFF_IDX + ((size_t)(bb * NCB + c)) * HW + t];
    zval[k] = z[((size_t)(bb * 128 + c * 16 + d)) * HW + t];
  }
  __syncthreads();  // zero-init visible

#pragma unroll
  for (int k = 0; k < 4; ++k) {
    atomicAdd(&s_sum[bidx[k]], zval[k]);  // ds_add_f32, banked
    if (d == 0) atomicAdd(&s_cnt[bidx[k]], 1.0f);
  }
  __syncthreads();

  ws_sums_p[((size_t)((c * CDIM + d) * 2 + half)) * VOCAB + t] = s_sum[t];
  if (d == 0) ws_counts_p[(c * 2 + half) * VOCAB + t] = s_cnt[t];
}

// k_update: exact v8. 64 blocks x 256 threads; block = (c, part).
__global__ __launch_bounds__(256) void k_update(
    const float* __restrict__ ema_count, const float* __restrict__ ema_weight,
    const float* __restrict__ ws_counts_p, const float* __restrict__ ws_sums_p,
    const float* __restrict__ ws_commit_arr, float* __restrict__ out) {
  const int c = blockIdx.x >> 3;
  const int part = blockIdx.x & 7;
  const int t = threadIdx.x;
  __shared__ float s_red[4];
  __shared__ float s_n;
  __shared__ double s_dred[4];

  const float* cp0 = ws_counts_p + (c * 2 + 0) * VOCAB;
  const float* cp1 = ws_counts_p + (c * 2 + 1) * VOCAB;

  float psum = 0.f;
#pragma unroll
  for (int k = 0; k < 4; ++k) {
    const int v = k * 256 + t;
    psum += 0.99f * ema_count[c * VOCAB + v] + 0.01f * (cp0[v] + cp1[v]);
  }
#pragma unroll
  for (int off = 32; off; off >>= 1) psum += __shfl_down(psum, off);
  if ((t & 63) == 0) s_red[t >> 6] = psum;
  __syncthreads();
  if (t == 0) s_n = (s_red[0] + s_red[1]) + (s_red[2] + s_red[3]);
  __syncthreads();
  const float nsum = s_n;
  const float veps = 0.01024f;  // VOCAB * 1e-5

  // new_count: 128 entries per block
  if (t < 128) {
    const int v = part * 128 + t;
    out[OFF_NCNT + c * VOCAB + v] =
        0.99f * ema_count[c * VOCAB + v] + 0.01f * (cp0[v] + cp1[v]);
  }

  // new_weight / new_codebooks: 2048 elements per block, coalesced stores;
  // sum partials read from [c][d][half][v] layout (L2-hot, 1MB total)
#pragma unroll
  for (int k = 0; k < 8; ++k) {
    const int i = part * 2048 + k * 256 + t;  // element within codebook c
    const int v = i >> 4;
    const int d = i & 15;
    const float nc =
        0.99f * ema_count[c * VOCAB + v] + 0.01f * (cp0[v] + cp1[v]);
    const float cnt = (nc + 1e-5f) / (nsum + veps) * nsum;
    const size_t gi = (size_t)c * VOCAB * CDIM + i;
    const float s0 = ws_sums_p[((size_t)((c * CDIM + d) * 2 + 0)) * VOCAB + v];
    const float s1 = ws_sums_p[((size_t)((c * CDIM + d) * 2 + 1)) * VOCAB + v];
    const float nw = 0.99f * ema_weight[gi] + 0.01f * (s0 + s1);
    out[OFF_NWT + gi] = nw;
    out[OFF_NCB + gi] = nw / cnt;
  }

  if (blockIdx.x == 0) {
    double ps = 0.0;
#pragma unroll
    for (int k = 0; k < 4; ++k) ps += (double)ws_commit_arr[k * 256 + t];
#pragma unroll
    for (int off = 32; off; off >>= 1) ps += __shfl_down(ps, off);
    if ((t & 63) == 0) s_dred[t >> 6] = ps;
    __syncthreads();
    if (t == 0)
      out[OFF_COMMIT] =
          (float)(((s_dred[0] + s_dred[1]) + (s_dred[2] + s_dred[3])) /
                  1048576.0);
  }
}

extern "C" void kernel_launch(void* const* d_in, const int* in_sizes, int n_in,
                              void* d_out, int out_size, void* d_ws,
                              size_t ws_size, hipStream_t stream) {
  const float* z = (const float*)d_in[0];
  const float* codebooks = (const float*)d_in[1];
  const float* ema_count = (const float*)d_in[2];
  const float* ema_weight = (const float*)d_in[3];
  float* out = (float*)d_out;

  float* wsf = (float*)d_ws;
  float* ws_counts_p = wsf + WS_CNTP_OFF;
  float* ws_sums_p = wsf + WS_SUMP_OFF;
  float* ws_commit_arr = wsf + WS_CARR_OFF;

  // no memset: all workspace words are written before being read

  k_assign<<<dim3(1024), dim3(512), 0, stream>>>(z, codebooks, out,
                                                 ws_commit_arr);
  k_stats<<<dim3(256), dim3(1024), 0, stream>>>(z, out, ws_counts_p,
                                                ws_sums_p);
  k_update<<<dim3(64), dim3(256), 0, stream>>>(ema_count, ema_weight,
                                               ws_counts_p, ws_sums_p,
                                               ws_commit_arr, out);
}

// Round 12
// 131.161 us; speedup vs baseline: 1.6503x; 1.0246x over previous
//
#include <hip/hip_runtime.h>

// SimVQuantizer: B=8, D=128 (N_CB=8 x CDIM=16), H=W=32 -> 8192 pixels.
// Outputs (FLOAT32, concatenated flat):
//   quantized  [8,128,32,32]  = 1048576   @ 0
//   indices    [8,8,32,32]    =   65536   @ 1048576
//   commitment scalar         =       1   @ 1114112
//   new_codebooks [8,1024,16] =  131072   @ 1114113
//   new_count  [8,1024]       =    8192   @ 1245185
//   new_weight [8,1024,16]    =  131072   @ 1253377

#define NCB   8
#define VOCAB 1024
#define CDIM  16
#define NPIX  8192   // B*H*W
#define HW    1024   // H*W

#define OFF_QUANT  0
#define OFF_IDX    1048576
#define OFF_COMMIT 1114112
#define OFF_NCB    1114113
#define OFF_NCNT   1245185
#define OFF_NWT    1253377

// workspace layout (floats):
//   counts_p [8][2][1024]      @ 0       (per-(c,half) partial counts)
//   sums_p   [8][16][2][1024]  @ 16384   (per-(c,d,half) partial sums)
//   commit_arr [512]           @ 278528  (per-assign-block partials)
// No memset: every word is written before it is read.
// Lessons pinned: no global atomics in hot paths (v6); no per-block
// __threadfence finisher patterns (v10); SMEM s_loads can't be counted-
// pipelined (out-of-order -> lgkmcnt(0) only); packed-f32 (f32x2) never
// reduces issue count on hipcc (v9, v12); R-blocking only works when
// entries stay in SGPRs (v2/v3 spilled with VGPR entry staging).
#define WS_CNTP_OFF 0
#define WS_SUMP_OFF (NCB * 2 * VOCAB)
#define WS_CARR_OFF (NCB * 2 * VOCAB + NCB * CDIM * 2 * VOCAB)

// numpy pairwise_sum (order-preserving 8-accumulator) for n=16:
// r[j] = a[j] + a[j+8];  res = ((r0+r1)+(r2+r3)) + ((r4+r5)+(r6+r7))
__device__ __forceinline__ float npsum16(const float m[16]) {
#pragma clang fp contract(off)
  float r0 = m[0] + m[8];
  float r1 = m[1] + m[9];
  float r2 = m[2] + m[10];
  float r3 = m[3] + m[11];
  float r4 = m[4] + m[12];
  float r5 = m[5] + m[13];
  float r6 = m[6] + m[14];
  float r7 = m[7] + m[15];
  return ((r0 + r1) + (r2 + r3)) + ((r4 + r5) + (r6 + r7));
}

__device__ __forceinline__ float npsum16sq(const float a[16]) {
#pragma clang fp contract(off)
  float m[16];
#pragma unroll
  for (int d = 0; d < 16; ++d) m[d] = a[d] * a[d];
  return npsum16(m);
}

// One entry's distance + argmin step. numpy einsum (optimize=False) npyv
// contig order for n=16, then (z2 - 2*dot) + c2 — bit-identical to v1.
__device__ __forceinline__ void proc_entry(const float zv[16],
                                           const float e[16], float c2v,
                                           float z2, int idx, float& best,
                                           int& bi) {
#pragma clang fp contract(off)
  float m[16];
#pragma unroll
  for (int d = 0; d < 16; ++d) m[d] = zv[d] * e[d];
  float l0 = (m[0] + m[4]) + (m[8] + m[12]);
  float l1 = (m[1] + m[5]) + (m[9] + m[13]);
  float l2 = (m[2] + m[6]) + (m[10] + m[14]);
  float l3 = (m[3] + m[7]) + (m[11] + m[15]);
  const float dot = (l0 + l1) + (l2 + l3);
  const float d2 = (z2 - 2.0f * dot) + c2v;
  const bool lt = d2 < best;  // strict: ascending scan -> first-wins
  best = lt ? d2 : best;
  bi = lt ? idx : bi;
}

// v13 k_assign: v8's SMEM-stream structure with R=2 pixel blocking.
// 512 blocks x 512 threads; block = (c, pchunk of 128 pixels). Each lane
// owns 2 pixels (zv[2][16] = 32 VGPR; entries stay in SGPRs so no VGPR
// staging -> no spill, unlike v2/v3). Per lgkmcnt(0) drain (the SMEM
// stall, ~200cy L2-hot) compute doubles (~296 -> ~592 cyc) and each entry
// feeds 2 independent dot chains -> stall fraction ~halves. Chip-wide
// VALU work unchanged; entry loads halve.
__global__ __launch_bounds__(512, 4) void k_assign(
    const float* __restrict__ z, const float* __restrict__ cb,
    float* __restrict__ out, float* __restrict__ ws_commit_arr) {
  __shared__ float s_c2[VOCAB];         // 4KB
  __shared__ float s_best[8 * 128];     // 4KB: per-wave cand per pixel
  __shared__ int s_bi[8 * 128];         // 4KB
  __shared__ float s_red[2];

  const int c = blockIdx.x >> 6;
  const int pchunk = blockIdx.x & 63;   // chunk of 128 pixels
  const int t = threadIdx.x;
  const int pix = t & 63;
  const int w = t >> 6;
  // provably wave-uniform wave id -> scalar (SGPR) entry addressing below
  const int wu = __builtin_amdgcn_readfirstlane(w);

  const float* cbc = cb + (size_t)c * VOCAB * CDIM;

  // ||cb||^2 for all 1024 entries (np.sum(cb*cb,-1), pairwise 8-acc order)
  for (int v = t; v < VOCAB; v += 512) {
    float e[16];
#pragma unroll
    for (int d = 0; d < 16; ++d) e[d] = cbc[(size_t)v * CDIM + d];
    s_c2[v] = npsum16sq(e);
  }

  const int nbase = pchunk * 128;   // first pixel id (128 | 1024 -> one b)
  const int b = nbase >> 10;        // batch
  const int hwb = nbase & 1023;     // base h*W + w

  // zv[r][d] = z[b, c*16+d, hwb + r*64 + pix]; 64-lane coalesced per (r,d)
  const float* zbase = z + ((size_t)(b * 128 + c * 16)) * HW + hwb + pix;
  float zv[2][16];
  float z2[2];
#pragma unroll
  for (int r = 0; r < 2; ++r) {
#pragma unroll
    for (int d = 0; d < 16; ++d) zv[r][d] = zbase[(size_t)d * HW + r * 64];
    z2[r] = npsum16sq(zv[r]);
  }

  __syncthreads();  // s_c2 ready

  // wave wu scans entries [wu*128, wu*128+128), ascending
  const int vbase = wu * 128;
  const float* ep = cbc + (size_t)vbase * CDIM;  // uniform (SGPR) pointer

  float best[2] = {INFINITY, INFINITY};
  int bi[2] = {0, 0};

#pragma unroll 2
  for (int k = 0; k < 128; k += 2) {
    // two entries per body (SGPR x16 loads); each feeds both pixels
    float ea[16], eb[16];
#pragma unroll
    for (int d = 0; d < 16; ++d) ea[d] = ep[(size_t)k * CDIM + d];
#pragma unroll
    for (int d = 0; d < 16; ++d) eb[d] = ep[(size_t)(k + 1) * CDIM + d];
    const float cv0 = s_c2[vbase + k];
    const float cv1 = s_c2[vbase + k + 1];
    proc_entry(zv[0], ea, cv0, z2[0], vbase + k, best[0], bi[0]);
    proc_entry(zv[1], ea, cv0, z2[1], vbase + k, best[1], bi[1]);
    proc_entry(zv[0], eb, cv1, z2[0], vbase + k + 1, best[0], bi[0]);
    proc_entry(zv[1], eb, cv1, z2[1], vbase + k + 1, best[1], bi[1]);
  }

#pragma unroll
  for (int r = 0; r < 2; ++r) {
    s_best[w * 128 + r * 64 + pix] = best[r];
    s_bi[w * 128 + r * 64 + pix] = bi[r];
  }
  __syncthreads();

  // threads 0..127 (waves 0,1): combine the 8 per-wave candidates for
  // pixel p_local = t. Wave slices are disjoint ascending ranges; break
  // float ties by lower index -> np.argmin first-wins exactly.
  if (t < 128) {
    const int r = t >> 6;  // this thread's own zv[r] IS pixel t's z
    float bb = s_best[t];
    int bbi = s_bi[t];
#pragma unroll
    for (int s = 1; s < 8; ++s) {
      const float ob = s_best[s * 128 + t];
      const int oi = s_bi[s * 128 + t];
      const bool take = (ob < bb) || (ob == bb && oi < bbi);
      bb = take ? ob : bb;
      bbi = take ? oi : bbi;
    }

    const int hw = hwb + t;  // pixel t's h*W+w (t = r*64 + pix)
    const float* qe = cbc + (size_t)bbi * CDIM;  // winning entry (L2-hot)
    float comm = 0.f;
#pragma unroll
    for (int d = 0; d < 16; ++d) {
      float zq = qe[d];
      float diff, qst;
      {
#pragma clang fp contract(off)
        diff = zv[r][d] - zq;
        qst = zv[r][d] + (zq - zv[r][d]);  // zq_st = zp + (zq - zp)
      }
      comm += diff * diff;
      out[OFF_QUANT + ((size_t)(b * 128 + c * 16 + d)) * HW + hw] = qst;
    }
    out[OFF_IDX + ((size_t)(b * NCB + c)) * HW + hw] = (float)bbi;

    // commitment partial: reduce waves 0,1 -> one plain store per block
#pragma unroll
    for (int off = 32; off; off >>= 1) comm += __shfl_down(comm, off);
    if ((t & 63) == 0) s_red[t >> 6] = comm;
  }
  __syncthreads();
  if (t == 0) ws_commit_arr[blockIdx.x] = s_red[0] + s_red[1];
}

// k_stats: exact v8 (proven fast). 256 blocks = (c, d, half) x 1024
// threads; hoisted loads (one latency exposure), LDS-atomic binning,
// dense partial writes, zero global atomics, zero fences.
__global__ __launch_bounds__(1024, 4) void k_stats(
    const float* __restrict__ z, const float* __restrict__ outbuf,
    float* __restrict__ ws_counts_p, float* __restrict__ ws_sums_p) {
  __shared__ float s_sum[VOCAB];  // 4KB
  __shared__ float s_cnt[VOCAB];  // 4KB (d==0 blocks only)
  const int c = blockIdx.x >> 5;
  const int d = (blockIdx.x >> 1) & 15;
  const int half = blockIdx.x & 1;
  const int t = threadIdx.x;

  s_sum[t] = 0.f;
  if (d == 0) s_cnt[t] = 0.f;

  // hoist all loads: 4 idx + 4 z, independent -> one latency exposure
  int bidx[4];
  float zval[4];
#pragma unroll
  for (int k = 0; k < 4; ++k) {
    const int bb = half * 4 + k;  // batch
    bidx[k] = (int)outbuf[OFF_IDX + ((size_t)(bb * NCB + c)) * HW + t];
    zval[k] = z[((size_t)(bb * 128 + c * 16 + d)) * HW + t];
  }
  __syncthreads();  // zero-init visible

#pragma unroll
  for (int k = 0; k < 4; ++k) {
    atomicAdd(&s_sum[bidx[k]], zval[k]);  // ds_add_f32, banked
    if (d == 0) atomicAdd(&s_cnt[bidx[k]], 1.0f);
  }
  __syncthreads();

  ws_sums_p[((size_t)((c * CDIM + d) * 2 + half)) * VOCAB + t] = s_sum[t];
  if (d == 0) ws_counts_p[(c * 2 + half) * VOCAB + t] = s_cnt[t];
}

// k_update: v8 with the commitment reduce adjusted to 512 partials.
__global__ __launch_bounds__(256) void k_update(
    const float* __restrict__ ema_count, const float* __restrict__ ema_weight,
    const float* __restrict__ ws_counts_p, const float* __restrict__ ws_sums_p,
    const float* __restrict__ ws_commit_arr, float* __restrict__ out) {
  const int c = blockIdx.x >> 3;
  const int part = blockIdx.x & 7;
  const int t = threadIdx.x;
  __shared__ float s_red[4];
  __shared__ float s_n;
  __shared__ double s_dred[4];

  const float* cp0 = ws_counts_p + (c * 2 + 0) * VOCAB;
  const float* cp1 = ws_counts_p + (c * 2 + 1) * VOCAB;

  float psum = 0.f;
#pragma unroll
  for (int k = 0; k < 4; ++k) {
    const int v = k * 256 + t;
    psum += 0.99f * ema_count[c * VOCAB + v] + 0.01f * (cp0[v] + cp1[v]);
  }
#pragma unroll
  for (int off = 32; off; off >>= 1) psum += __shfl_down(psum, off);
  if ((t & 63) == 0) s_red[t >> 6] = psum;
  __syncthreads();
  if (t == 0) s_n = (s_red[0] + s_red[1]) + (s_red[2] + s_red[3]);
  __syncthreads();
  const float nsum = s_n;
  const float veps = 0.01024f;  // VOCAB * 1e-5

  // new_count: 128 entries per block
  if (t < 128) {
    const int v = part * 128 + t;
    out[OFF_NCNT + c * VOCAB + v] =
        0.99f * ema_count[c * VOCAB + v] + 0.01f * (cp0[v] + cp1[v]);
  }

  // new_weight / new_codebooks: 2048 elements per block, coalesced stores;
  // sum partials read from [c][d][half][v] layout (L2-hot, 1MB total)
#pragma unroll
  for (int k = 0; k < 8; ++k) {
    const int i = part * 2048 + k * 256 + t;  // element within codebook c
    const int v = i >> 4;
    const int d = i & 15;
    const float nc =
        0.99f * ema_count[c * VOCAB + v] + 0.01f * (cp0[v] + cp1[v]);
    const float cnt = (nc + 1e-5f) / (nsum + veps) * nsum;
    const size_t gi = (size_t)c * VOCAB * CDIM + i;
    const float s0 = ws_sums_p[((size_t)((c * CDIM + d) * 2 + 0)) * VOCAB + v];
    const float s1 = ws_sums_p[((size_t)((c * CDIM + d) * 2 + 1)) * VOCAB + v];
    const float nw = 0.99f * ema_weight[gi] + 0.01f * (s0 + s1);
    out[OFF_NWT + gi] = nw;
    out[OFF_NCB + gi] = nw / cnt;
  }

  if (blockIdx.x == 0) {
    double ps = 0.0;
#pragma unroll
    for (int k = 0; k < 2; ++k) ps += (double)ws_commit_arr[k * 256 + t];
#pragma unroll
    for (int off = 32; off; off >>= 1) ps += __shfl_down(ps, off);
    if ((t & 63) == 0) s_dred[t >> 6] = ps;
    __syncthreads();
    if (t == 0)
      out[OFF_COMMIT] =
          (float)(((s_dred[0] + s_dred[1]) + (s_dred[2] + s_dred[3])) /
                  1048576.0);
  }
}

extern "C" void kernel_launch(void* const* d_in, const int* in_sizes, int n_in,
                              void* d_out, int out_size, void* d_ws,
                              size_t ws_size, hipStream_t stream) {
  const float* z = (const float*)d_in[0];
  const float* codebooks = (const float*)d_in[1];
  const float* ema_count = (const float*)d_in[2];
  const float* ema_weight = (const float*)d_in[3];
  float* out = (float*)d_out;

  float* wsf = (float*)d_ws;
  float* ws_counts_p = wsf + WS_CNTP_OFF;
  float* ws_sums_p = wsf + WS_SUMP_OFF;
  float* ws_commit_arr = wsf + WS_CARR_OFF;

  // no memset: all workspace words are written before being read

  k_assign<<<dim3(512), dim3(512), 0, stream>>>(z, codebooks, out,
                                                ws_commit_arr);
  k_stats<<<dim3(256), dim3(1024), 0, stream>>>(z, out, ws_counts_p,
                                                ws_sums_p);
  k_update<<<dim3(64), dim3(256), 0, stream>>>(ema_count, ema_weight,
                                               ws_counts_p, ws_sums_p,
                                               ws_commit_arr, out);
}